// Round 15
// baseline (478.255 us; speedup 1.0000x reference)
//
#include <hip/hip_runtime.h>

#define DD 1024

typedef int   i32x4  __attribute__((ext_vector_type(4)));
typedef int   i32x8  __attribute__((ext_vector_type(8)));
typedef float f32x16 __attribute__((ext_vector_type(16)));

__device__ __forceinline__ float sigm(float x) { return 1.0f / (1.0f + __expf(-x)); }
__device__ __forceinline__ float tanh_fast(float x) {
  float e = __expf(-2.0f * fabsf(x));
  float t = (1.0f - e) / (1.0f + e);
  return copysignf(t, x);
}
__device__ __forceinline__ void gload_lds16(const void* g, void* l) {
  __builtin_amdgcn_global_load_lds((const __attribute__((address_space(1))) void*)g,
                                   (__attribute__((address_space(3))) void*)l, 16, 0, 0);
}
__device__ __forceinline__ unsigned pk_fp8x4(float a, float b, float c, float d) {
  int u = __builtin_amdgcn_cvt_pk_fp8_f32(a, b, 0, false);
  u = __builtin_amdgcn_cvt_pk_fp8_f32(c, d, u, true);
  return (unsigned)u;
}

// Fragment image, BK=64: 8 KB per (128-row, 64-k) K-tile.
//   within-tile addr(r, kk) = (r>>3)*512 + (kk>>4)*128 + (r&7)*16 + (kk&15)
//   full addr = blk*131072 + kt*8192 + within   (kt = k>>6, kk = k&63)
// A image: blk = rb (row-block). B image: blk = db; B row n_t = gate*32 + dgl.

// ---- one-time weight prep: tiled B image + bias[4][1024] ----
__global__ __launch_bounds__(256) void prep_weights(
    const float* __restrict__ Wih, const float* __restrict__ Whh,
    const float* __restrict__ bih, const float* __restrict__ bhh,
    unsigned char* __restrict__ Wcat8, float* __restrict__ bias) {
  int i = blockIdx.x * 256 + threadIdx.x;
  int g = i >> 18;
  int rem = i & 262143;
  int n = rem >> 8;
  int k4 = rem & 255;
  const float4* wih4 = reinterpret_cast<const float4*>(Wih);
  const float4* whh4 = reinterpret_cast<const float4*>(Whh);
  float4 v;
  if (g == 0) {
    size_t idx = (size_t)n * 256 + k4;
    float4 a = wih4[idx], b = whh4[idx];
    v = make_float4(a.x + b.x, a.y + b.y, a.z + b.z, a.w + b.w);
  } else if (g == 1) {
    size_t idx = (size_t)(DD + n) * 256 + k4;
    float4 a = wih4[idx], b = whh4[idx];
    v = make_float4(a.x + b.x, a.y + b.y, a.z + b.z, a.w + b.w);
  } else if (g == 2) {
    size_t idx = (size_t)(2 * DD + n) * 256 + k4;
    v = wih4[idx];
  } else {
    size_t idx = (size_t)(2 * DD + n) * 256 + k4;
    v = whh4[idx];
  }
  unsigned pkd = pk_fp8x4(v.x * 32.0f, v.y * 32.0f, v.z * 32.0f, v.w * 32.0f);

  int db  = n >> 5;
  int n_t = g * 32 + (n & 31);
  size_t addr = (size_t)db * 131072 + (size_t)(k4 >> 4) * 8192 +
                (n_t >> 3) * 512 + ((k4 >> 2) & 3) * 128 + (n_t & 7) * 16 +
                (k4 & 3) * 4;
  *reinterpret_cast<unsigned*>(Wcat8 + addr) = pkd;

  if (i < 4 * DD) {
    int bg = i >> 10, bn = i & 1023;
    float bv;
    if (bg == 0)      bv = bih[bn] + bhh[bn];
    else if (bg == 1) bv = bih[DD + bn] + bhh[DD + bn];
    else if (bg == 2) bv = bih[2 * DD + bn];
    else              bv = bhh[2 * DD + bn];
    bias[i] = bv;
  }
}

// ---- error GEMV + fp8 cast of state into tiled A image ----
__global__ __launch_bounds__(256) void error_cast(
    const float* S, const float* __restrict__ We, const float* __restrict__ be,
    unsigned char* __restrict__ Sb8, float* __restrict__ err) {
  __shared__ float part[4];
  const int row = blockIdx.x;
  const int t = threadIdx.x;                // k = 4t
  float4 v = reinterpret_cast<const float4*>(S + (size_t)row * DD)[t];
  float4 w = reinterpret_cast<const float4*>(We)[t];
  float dot = v.x * w.x + v.y * w.y + v.z * w.z + v.w * w.w;

  int r = row & 127;
  size_t addr = (size_t)(row >> 7) * 131072 + (size_t)(t >> 4) * 8192 +
                (r >> 3) * 512 + ((t >> 2) & 3) * 128 + (r & 7) * 16 +
                (t & 3) * 4;
  *reinterpret_cast<unsigned*>(Sb8 + addr) = pk_fp8x4(v.x, v.y, v.z, v.w);

#pragma unroll
  for (int off = 32; off > 0; off >>= 1) dot += __shfl_xor(dot, off);
  if ((t & 63) == 0) part[t >> 6] = dot;
  __syncthreads();
  if (t == 0) err[row] = sigm(part[0] + part[1] + part[2] + part[3] + be[0]);
}

// ---- reduce per-db partial dots -> err = sigmoid(sum + be) ----
__global__ __launch_bounds__(256) void sigmoid_err(
    const float* __restrict__ errp, const float* __restrict__ be,
    float* __restrict__ err, int M) {
  int m = blockIdx.x * 256 + threadIdx.x;
  if (m >= M) return;
  const float4* p = reinterpret_cast<const float4*>(errp + (size_t)m * 32);
  float s = 0.f;
#pragma unroll
  for (int i = 0; i < 8; ++i) { float4 q = p[i]; s += q.x + q.y + q.z + q.w; }
  err[m] = sigm(s + be[0]);
}

// ---- fused 4-gate MX-fp8 GEMM + GRU epilogue (R13 structure, untouched loop) ----
// Tile 128M x 128N(4g x 32dg), BK=64, 16 K-tiles, 4 waves; wave = 32M x 128N
// via 4x mfma_scale_f32_32x32x64_f8f6f4 (A scale 1.0=127, B scale 2^-5=122).
// FUSE epilogue (iter-1 only): writes next-iter fp8 A-image bytes (unique
// writer per element) + per-db partial err dots via intra-half shfl reduce.
template <bool FUSE>
__global__ __launch_bounds__(256, 4) void gru_fused_gemm(
    const unsigned char* __restrict__ Sb8,   // tiled A image
    const unsigned char* __restrict__ Wcat8, // tiled B image
    const float* __restrict__ bias,          // [4096]
    const float* __restrict__ err,           // [M]
    const float* Sf,                         // [M][1024] f32 h (may alias out)
    float* out,
    const float* __restrict__ We,            // [1024]      (FUSE)
    float* __restrict__ errp,                // [M][32]     (FUSE)
    unsigned char* __restrict__ SbOut,       // next A image (FUSE)
    int M) {
  __shared__ alignas(16) unsigned char As[2 * 8192];   // 16 KB
  __shared__ alignas(16) unsigned char Bs[2 * 8192];   // 16 KB

  const int bid = blockIdx.x;
  const int x = bid & 7;
  const int c = bid >> 3;
  const int db = (x & 1) * 16 + (c & 15);
  const int rb = (x >> 1) * 64 + (c >> 4);

  const int tid = threadIdx.x;
  const int w = tid >> 6;
  const int lane = tid & 63;
  const int l31 = lane & 31;
  const int h = lane >> 5;

  const unsigned char* sA0 = Sb8 + (size_t)rb * 131072 + (size_t)w * 1024 + lane * 16;
  const unsigned char* sB0 = Wcat8 + (size_t)db * 131072 + (size_t)w * 1024 + lane * 16;
  unsigned char* const dA0 = As + w * 1024;
  unsigned char* const dB0 = Bs + w * 1024;

  const int ar = w * 32 + l31;
  const int aoff = (ar >> 3) * 512 + (2 * h) * 128 + (ar & 7) * 16;
  int boff[4];
#pragma unroll
  for (int g = 0; g < 4; ++g) {
    int br = g * 32 + l31;
    boff[g] = (br >> 3) * 512 + (2 * h) * 128 + (br & 7) * 16;
  }

  f32x16 acc[4];
#pragma unroll
  for (int g = 0; g < 4; ++g)
#pragma unroll
    for (int r = 0; r < 16; ++r) acc[g][r] = 0.0f;

  auto stage = [&](int t) {
    const int slot = (t & 1) * 8192;
    const size_t koff = (size_t)t * 8192;
    gload_lds16(sA0 + koff, dA0 + slot);
    gload_lds16(sA0 + koff + 4096, dA0 + slot + 4096);
    gload_lds16(sB0 + koff, dB0 + slot);
    gload_lds16(sB0 + koff + 4096, dB0 + slot + 4096);
  };

  stage(0);
  stage(1);

#pragma unroll
  for (int t = 0; t < 16; ++t) {
    const int sb = (t & 1) * 8192;
    if (t < 15) asm volatile("s_waitcnt vmcnt(4)" ::: "memory");
    else        asm volatile("s_waitcnt vmcnt(0)" ::: "memory");
    __builtin_amdgcn_s_barrier();

    const unsigned char* Ab = As + sb;
    const unsigned char* Bb = Bs + sb;
    i32x4 a0 = *reinterpret_cast<const i32x4*>(Ab + aoff);
    i32x4 a1 = *reinterpret_cast<const i32x4*>(Ab + aoff + 128);
    i32x8 a = __builtin_shufflevector(a0, a1, 0, 1, 2, 3, 4, 5, 6, 7);
    i32x8 bf[4];
#pragma unroll
    for (int g = 0; g < 4; ++g) {
      i32x4 b0 = *reinterpret_cast<const i32x4*>(Bb + boff[g]);
      i32x4 b1 = *reinterpret_cast<const i32x4*>(Bb + boff[g] + 128);
      bf[g] = __builtin_shufflevector(b0, b1, 0, 1, 2, 3, 4, 5, 6, 7);
    }
    asm volatile("s_waitcnt lgkmcnt(0)" ::: "memory");
    __builtin_amdgcn_s_barrier();               // slot sb free block-wide

    if (t <= 13) stage(t + 2);

    __builtin_amdgcn_s_setprio(1);
#pragma unroll
    for (int g = 0; g < 4; ++g)
      acc[g] = __builtin_amdgcn_mfma_scale_f32_32x32x64_f8f6f4(
          a, bf[g], acc[g], 0, 0, 0, 127, 0, 122);
    __builtin_amdgcn_s_setprio(0);
  }

  // ---- epilogue: r,z,n + out = h + e*(1-z)*(n-h)   [+ fused err/cast]
  // C/D 32x32 layout: col = lane&31, row = (reg&3) + 8*(reg>>2) + 4*(lane>>5)
  const int dgcol = db * 32 + l31;
  const float b_r = bias[dgcol];
  const float b_z = bias[DD + dgcol];
  const float b_i = bias[2 * DD + dgcol];
  const float b_h = bias[3 * DD + dgcol];
  float We_c = 0.f;
  size_t kpart = 0;
  if constexpr (FUSE) {
    We_c = We[dgcol];
    kpart = (size_t)(dgcol >> 6) * 8192 + ((dgcol >> 4) & 3) * 128 + (dgcol & 15);
  }
#pragma unroll
  for (int reg = 0; reg < 16; ++reg) {
    int rowf = (reg & 3) + 8 * (reg >> 2) + 4 * h;
    int m = rb * 128 + w * 32 + rowf;
    float e = err[m];
    float hh = Sf[(size_t)m * DD + dgcol];
    float r = sigm(acc[0][reg] + b_r);
    float z = sigm(acc[1][reg] + b_z);
    float n = tanh_fast(acc[2][reg] + b_i + r * (acc[3][reg] + b_h));
    float o = hh + e * (1.0f - z) * (n - hh);
    out[(size_t)m * DD + dgcol] = o;
    if constexpr (FUSE) {
      int rr = m & 127;
      SbOut[(size_t)(m >> 7) * 131072 + kpart + (rr >> 3) * 512 + (rr & 7) * 16] =
          (unsigned char)(__builtin_amdgcn_cvt_pk_fp8_f32(o, o, 0, false) & 0xFF);
      float v = o * We_c;                       // partial err dot over this db's 32 cols
      v += __shfl_xor(v, 1);
      v += __shfl_xor(v, 2);
      v += __shfl_xor(v, 4);
      v += __shfl_xor(v, 8);
      v += __shfl_xor(v, 16);                   // stays within 32-lane half
      if (l31 == 0) errp[(size_t)m * 32 + db] = v;
    }
  }
}

extern "C" void kernel_launch(void* const* d_in, const int* in_sizes, int n_in,
                              void* d_out, int out_size, void* d_ws, size_t ws_size,
                              hipStream_t stream) {
  const float* x   = (const float*)d_in[0];
  const float* Wih = (const float*)d_in[1];
  const float* Whh = (const float*)d_in[2];
  const float* bih = (const float*)d_in[3];
  const float* bhh = (const float*)d_in[4];
  const float* We  = (const float*)d_in[5];
  const float* be  = (const float*)d_in[6];
  float* out = (float*)d_out;
  const int M = in_sizes[0] / DD;   // 32768
  const int nwg = (M / 128) * 32;   // 8192

  char* ws = (char*)d_ws;
  const size_t SZ_IMG = (size_t)M * DD;   // 32 MB
  const size_t off_SbB  = SZ_IMG;
  const size_t off_W    = 2 * SZ_IMG;
  const size_t off_bias = off_W + 4194304;
  const size_t off_errp = off_bias + 16384;
  const size_t off_err  = off_errp + (size_t)M * 32 * 4;
  const size_t need_full = off_err + (size_t)M * 4;

  if (ws_size >= need_full) {
    unsigned char* SbA   = (unsigned char*)ws;
    unsigned char* SbB   = (unsigned char*)(ws + off_SbB);
    unsigned char* Wcat8 = (unsigned char*)(ws + off_W);
    float* bias = (float*)(ws + off_bias);
    float* errp = (float*)(ws + off_errp);
    float* err  = (float*)(ws + off_err);

    prep_weights<<<4096, 256, 0, stream>>>(Wih, Whh, bih, bhh, Wcat8, bias);
    error_cast<<<M, 256, 0, stream>>>(x, We, be, SbA, err);
    gru_fused_gemm<true><<<nwg, 256, 0, stream>>>(SbA, Wcat8, bias, err, x, out,
                                                  We, errp, SbB, M);
    sigmoid_err<<<(M + 255) / 256, 256, 0, stream>>>(errp, be, err, M);
    gru_fused_gemm<false><<<nwg, 256, 0, stream>>>(SbB, Wcat8, bias, err, out, out,
                                                   nullptr, nullptr, nullptr, M);
  } else {
    // fallback: R14 split path (36.3 MB)
    unsigned char* SbA   = (unsigned char*)ws;
    unsigned char* Wcat8 = (unsigned char*)(ws + SZ_IMG);
    float* bias = (float*)(ws + SZ_IMG + 4194304);
    float* err  = (float*)(ws + SZ_IMG + 4194304 + 16384);

    prep_weights<<<4096, 256, 0, stream>>>(Wih, Whh, bih, bhh, Wcat8, bias);
    const float* S = x;
    for (int it = 0; it < 2; ++it) {
      error_cast<<<M, 256, 0, stream>>>(S, We, be, SbA, err);
      gru_fused_gemm<false><<<nwg, 256, 0, stream>>>(SbA, Wcat8, bias, err, S, out,
                                                     nullptr, nullptr, nullptr, M);
      S = out;
    }
  }
}

// Round 16
// 439.896 us; speedup vs baseline: 1.0872x; 1.0872x over previous
//
#include <hip/hip_runtime.h>

#define DD 1024

typedef int   i32x4  __attribute__((ext_vector_type(4)));
typedef int   i32x8  __attribute__((ext_vector_type(8)));
typedef float f32x16 __attribute__((ext_vector_type(16)));

__device__ __forceinline__ float sigm(float x) { return 1.0f / (1.0f + __expf(-x)); }
__device__ __forceinline__ float tanh_fast(float x) {
  float e = __expf(-2.0f * fabsf(x));
  float t = (1.0f - e) / (1.0f + e);
  return copysignf(t, x);
}
__device__ __forceinline__ void gload_lds16(const void* g, void* l) {
  __builtin_amdgcn_global_load_lds((const __attribute__((address_space(1))) void*)g,
                                   (__attribute__((address_space(3))) void*)l, 16, 0, 0);
}
__device__ __forceinline__ unsigned pk_fp8x4(float a, float b, float c, float d) {
  int u = __builtin_amdgcn_cvt_pk_fp8_f32(a, b, 0, false);
  u = __builtin_amdgcn_cvt_pk_fp8_f32(c, d, u, true);
  return (unsigned)u;
}

// Fragment image, BK=64: 8 KB per (128-row, 64-k) K-tile, LANE-LINEAR reads.
//   subtile = 32 rows x 64 kk = 2 KB; within-subtile:
//     addr(r, gran) = sel(gran)*512 + (r&31)*16 + (kk&15),
//     sel(g) = ((g&1)<<1)|(g>>1)   (order: g0, g2, g1, g3)
//   full addr = blk*131072 + kt*8192 + rowgroup*2048 + within
// => fragment read a0 = h*512 + l31*16 (contiguous 1 KB per wave), a1 = +1024.
// A image: blk = rb, rowgroup = (r>>5). B image: blk = db, rowgroup = gate
// (n_t = gate*32 + dgl). Staging: image order == LDS order -> linear copy.

// ---- one-time weight prep: tiled B image + bias[4][1024] ----
// g=0: Wih_r+Whh_r ; g=1: Wih_z+Whh_z ; g=2: Wih_n ; g=3: Whh_n
__global__ __launch_bounds__(256) void prep_weights(
    const float* __restrict__ Wih, const float* __restrict__ Whh,
    const float* __restrict__ bih, const float* __restrict__ bhh,
    unsigned char* __restrict__ Wcat8, float* __restrict__ bias) {
  int i = blockIdx.x * 256 + threadIdx.x;
  int g = i >> 18;
  int rem = i & 262143;
  int n = rem >> 8;
  int k4 = rem & 255;                       // k = 4*k4
  const float4* wih4 = reinterpret_cast<const float4*>(Wih);
  const float4* whh4 = reinterpret_cast<const float4*>(Whh);
  float4 v;
  if (g == 0) {
    size_t idx = (size_t)n * 256 + k4;
    float4 a = wih4[idx], b = whh4[idx];
    v = make_float4(a.x + b.x, a.y + b.y, a.z + b.z, a.w + b.w);
  } else if (g == 1) {
    size_t idx = (size_t)(DD + n) * 256 + k4;
    float4 a = wih4[idx], b = whh4[idx];
    v = make_float4(a.x + b.x, a.y + b.y, a.z + b.z, a.w + b.w);
  } else if (g == 2) {
    size_t idx = (size_t)(2 * DD + n) * 256 + k4;
    v = wih4[idx];
  } else {
    size_t idx = (size_t)(2 * DD + n) * 256 + k4;
    v = whh4[idx];
  }
  // scale x32 (exact) so weights leave e4m3 denormal zone; MX B-scale 2^-5 undoes it
  unsigned pkd = pk_fp8x4(v.x * 32.0f, v.y * 32.0f, v.z * 32.0f, v.w * 32.0f);

  int db   = n >> 5;
  int dgl  = n & 31;                        // row within gate group
  int kt   = k4 >> 4;
  int gran = (k4 >> 2) & 3;
  int sel  = ((gran & 1) << 1) | (gran >> 1);
  int klo  = (k4 & 3) * 4;
  size_t addr = (size_t)db * 131072 + (size_t)kt * 8192 + g * 2048 +
                sel * 512 + dgl * 16 + klo;
  *reinterpret_cast<unsigned*>(Wcat8 + addr) = pkd;

  if (i < 4 * DD) {
    int bg = i >> 10, bn = i & 1023;
    float bv;
    if (bg == 0)      bv = bih[bn] + bhh[bn];
    else if (bg == 1) bv = bih[DD + bn] + bhh[DD + bn];
    else if (bg == 2) bv = bih[2 * DD + bn];
    else              bv = bhh[2 * DD + bn];
    bias[i] = bv;
  }
}

// ---- per-iteration: error GEMV + fp8 cast of state into tiled A image ----
__global__ __launch_bounds__(256) void error_cast(
    const float* S, const float* __restrict__ We, const float* __restrict__ be,
    unsigned char* __restrict__ Sb8, float* __restrict__ err) {
  __shared__ float part[4];
  const int row = blockIdx.x;
  const int t = threadIdx.x;                // k = 4t
  float4 v = reinterpret_cast<const float4*>(S + (size_t)row * DD)[t];
  float4 w = reinterpret_cast<const float4*>(We)[t];
  float dot = v.x * w.x + v.y * w.y + v.z * w.z + v.w * w.w;

  int r    = row & 127;
  int kt   = t >> 4;
  int gran = (t >> 2) & 3;
  int sel  = ((gran & 1) << 1) | (gran >> 1);
  int klo  = (t & 3) * 4;
  size_t addr = (size_t)(row >> 7) * 131072 + (size_t)kt * 8192 +
                (r >> 5) * 2048 + sel * 512 + (r & 31) * 16 + klo;
  *reinterpret_cast<unsigned*>(Sb8 + addr) = pk_fp8x4(v.x, v.y, v.z, v.w);

#pragma unroll
  for (int off = 32; off > 0; off >>= 1) dot += __shfl_xor(dot, off);
  if ((t & 63) == 0) part[t >> 6] = dot;
  __syncthreads();
  if (t == 0) err[row] = sigm(part[0] + part[1] + part[2] + part[3] + be[0]);
}

// ---- fused 4-gate MX-fp8 GEMM + GRU epilogue (R13 loop, lane-linear LDS) ----
// Tile 128M x 128N(4g x 32dg), BK=64, 16 K-tiles, 4 waves; wave = 32M x 128N
// via 4x mfma_scale_f32_32x32x64_f8f6f4 (A scale 1.0=127, B scale 2^-5=122).
// Every ds_read_b128 is a contiguous 1 KB wave read (lane*16) -> conflict-free.
__global__ __launch_bounds__(256, 4) void gru_fused_gemm(
    const unsigned char* __restrict__ Sb8,   // tiled A image
    const unsigned char* __restrict__ Wcat8, // tiled B image
    const float* __restrict__ bias,          // [4096]
    const float* __restrict__ err,           // [M]
    const float* Sf,                         // [M][1024] f32 h (may alias out)
    float* out, int M) {
  __shared__ alignas(16) unsigned char As[2 * 8192];   // 16 KB
  __shared__ alignas(16) unsigned char Bs[2 * 8192];   // 16 KB

  // two-level XCD decode: xcd owns 16db x 64rb, db fast (proven FETCH win)
  const int bid = blockIdx.x;
  const int x = bid & 7;
  const int c = bid >> 3;
  const int db = (x & 1) * 16 + (c & 15);
  const int rb = (x >> 1) * 64 + (c >> 4);

  const int tid = threadIdx.x;
  const int w = tid >> 6;                  // 0..3 ; wave owns M rows w*32..+31
  const int lane = tid & 63;
  const int l31 = lane & 31;
  const int h = lane >> 5;

  // staging: wave w copies bytes [w*1024, +1KB) and [+4KB) of each 8KB tile
  const unsigned char* sA0 = Sb8 + (size_t)rb * 131072 + (size_t)w * 1024 + lane * 16;
  const unsigned char* sB0 = Wcat8 + (size_t)db * 131072 + (size_t)w * 1024 + lane * 16;
  unsigned char* const dA0 = As + w * 1024;
  unsigned char* const dB0 = Bs + w * 1024;

  // lane-linear frag read offsets: a0 @ rowgroup*2048 + h*512 + l31*16, a1 = +1024
  const int aoff = w * 2048 + h * 512 + l31 * 16;
  const int bq = h * 512 + l31 * 16;       // + g*2048 per gate

  f32x16 acc[4];
#pragma unroll
  for (int g = 0; g < 4; ++g)
#pragma unroll
    for (int r = 0; r < 16; ++r) acc[g][r] = 0.0f;

  auto stage = [&](int t) {
    const int slot = (t & 1) * 8192;
    const size_t koff = (size_t)t * 8192;
    gload_lds16(sA0 + koff, dA0 + slot);
    gload_lds16(sA0 + koff + 4096, dA0 + slot + 4096);
    gload_lds16(sB0 + koff, dB0 + slot);
    gload_lds16(sB0 + koff + 4096, dB0 + slot + 4096);
  };

  stage(0);
  stage(1);

#pragma unroll
  for (int t = 0; t < 16; ++t) {
    const int sb = (t & 1) * 8192;
    if (t < 15) asm volatile("s_waitcnt vmcnt(4)" ::: "memory");
    else        asm volatile("s_waitcnt vmcnt(0)" ::: "memory");
    __builtin_amdgcn_s_barrier();

    const unsigned char* Ab = As + sb;
    const unsigned char* Bb = Bs + sb;
    i32x4 a0 = *reinterpret_cast<const i32x4*>(Ab + aoff);
    i32x4 a1 = *reinterpret_cast<const i32x4*>(Ab + aoff + 1024);
    i32x8 a = __builtin_shufflevector(a0, a1, 0, 1, 2, 3, 4, 5, 6, 7);
    i32x8 bf[4];
#pragma unroll
    for (int g = 0; g < 4; ++g) {
      i32x4 b0 = *reinterpret_cast<const i32x4*>(Bb + g * 2048 + bq);
      i32x4 b1 = *reinterpret_cast<const i32x4*>(Bb + g * 2048 + bq + 1024);
      bf[g] = __builtin_shufflevector(b0, b1, 0, 1, 2, 3, 4, 5, 6, 7);
    }
    asm volatile("s_waitcnt lgkmcnt(0)" ::: "memory");
    __builtin_amdgcn_s_barrier();               // slot sb free block-wide

    if (t <= 13) stage(t + 2);                  // into freed slot sb

    __builtin_amdgcn_s_setprio(1);
#pragma unroll
    for (int g = 0; g < 4; ++g)
      acc[g] = __builtin_amdgcn_mfma_scale_f32_32x32x64_f8f6f4(
          a, bf[g], acc[g], 0, 0, 0, 127, 0, 122);
    __builtin_amdgcn_s_setprio(0);
  }

  // ---- epilogue: r,z,n + out = h + e*(1-z)*(n-h)
  // C/D 32x32 layout: col = lane&31, row = (reg&3) + 8*(reg>>2) + 4*(lane>>5)
  const int dgcol = db * 32 + l31;
  const float b_r = bias[dgcol];
  const float b_z = bias[DD + dgcol];
  const float b_i = bias[2 * DD + dgcol];
  const float b_h = bias[3 * DD + dgcol];
#pragma unroll
  for (int reg = 0; reg < 16; ++reg) {
    int rowf = (reg & 3) + 8 * (reg >> 2) + 4 * h;
    int m = rb * 128 + w * 32 + rowf;
    float e = err[m];
    float hh = Sf[(size_t)m * DD + dgcol];
    float r = sigm(acc[0][reg] + b_r);
    float z = sigm(acc[1][reg] + b_z);
    float n = tanh_fast(acc[2][reg] + b_i + r * (acc[3][reg] + b_h));
    out[(size_t)m * DD + dgcol] = hh + e * (1.0f - z) * (n - hh);
  }
}

extern "C" void kernel_launch(void* const* d_in, const int* in_sizes, int n_in,
                              void* d_out, int out_size, void* d_ws, size_t ws_size,
                              hipStream_t stream) {
  const float* x   = (const float*)d_in[0];
  const float* Wih = (const float*)d_in[1];
  const float* Whh = (const float*)d_in[2];
  const float* bih = (const float*)d_in[3];
  const float* bhh = (const float*)d_in[4];
  const float* We  = (const float*)d_in[5];
  const float* be  = (const float*)d_in[6];
  float* out = (float*)d_out;
  const int M = in_sizes[0] / DD;   // 32768

  char* ws = (char*)d_ws;
  unsigned char* Sb8   = (unsigned char*)ws;                         // 32 MB (tiled)
  unsigned char* Wcat8 = (unsigned char*)(ws + (size_t)M * DD);      // 4 MB (tiled)
  float* bias = (float*)(ws + (size_t)M * DD + (size_t)4 * DD * DD);
  float* err  = (float*)(ws + (size_t)M * DD + (size_t)4 * DD * DD + (size_t)4 * DD * 4);

  prep_weights<<<4096, 256, 0, stream>>>(Wih, Whh, bih, bhh, Wcat8, bias);

  const int nwg = (M / 128) * 32;   // 8192
  const float* S = x;
  for (int it = 0; it < 2; ++it) {
    error_cast<<<M, 256, 0, stream>>>(S, We, be, Sb8, err);
    gru_fused_gemm<<<nwg, 256, 0, stream>>>(Sb8, Wcat8, bias, err, S, out, M);
    S = out;
  }
}